// Round 8
// baseline (144.452 us; speedup 1.0000x reference)
//
#include <hip/hip_runtime.h>
#include <hip/hip_fp16.h>
#include <math.h>

#define NB  8
#define CIN 64
#define HH  112
#define WW  112
#define OC  64
#define HWSZ (HH*WW)
#define NPOS (NB*HWSZ)

// patch geometry: 4 output rows per block, 16 cols
// rows hoB-2 .. hoB+6, cols wo0-2 .. wo0+18 (full coverage for |off|<1)
#define PR 9
#define PC 21
#define NPOSP (PR*PC)          // 189 positions
#define PATCH_CHUNKS (NPOSP*8) // 1512 x 16B = 24,192 B

#define TP_BLOCKS (HWSZ/64*NB) // 1568 transpose blocks

typedef unsigned short u16;
typedef __attribute__((ext_vector_type(8))) _Float16 h8;
typedef __attribute__((ext_vector_type(4))) float floatx4;

#define XT_ELEMS   (NB*HWSZ*CIN)   // 6,422,528 u16 (12.25 MB fp16)
#define WSWZ_ELEMS (18*4*64*8)     // 36,864 u16
#define OSWZ_ELEMS (18*4*32*8)     // 18,432 u16

union CV { uint4 u; h8 h; };

__device__ __forceinline__ u16 f2h(float f) { return __half_as_ushort(__float2half(f)); }
__device__ __forceinline__ __half2 H2(unsigned v) { union { unsigned u; __half2 h; } c; c.u = v; return c.h; }
__device__ __forceinline__ unsigned U2(__half2 h) { union { unsigned u; __half2 h; } c; c.h = h; return c.u; }
__device__ __forceinline__ unsigned pkh(float lo, float hi) {
    union { __half2 h; unsigned u; } c;
    c.h = __floats2half2_rn(lo, hi);
    return c.u;
}

struct TapW { __half2 w00, w01, w10, w11; };

// ---------- prep: transpose (NCHW f32 -> NHWC fp16) + weight swizzle ----------
__global__ __launch_bounds__(256) void prep_k(
    const float* __restrict__ x, const float* __restrict__ wgt,
    const float* __restrict__ offw,
    u16* __restrict__ xt, u16* __restrict__ wswz, u16* __restrict__ oswz)
{
    __shared__ float t[64][65];
    const int tid = threadIdx.x;
    const int bid = blockIdx.x;
    if (bid < TP_BLOCKS) {
        const int n   = bid & 7;          // XCD k handles image k
        const int hw0 = (bid >> 3) * 64;
        const int wv  = tid & 63;
        const int g   = tid >> 6;
        #pragma unroll
        for (int i = 0; i < 16; ++i) {
            const int c = i*4 + g;
            t[c][wv] = x[((size_t)n*CIN + c)*HWSZ + hw0 + wv];
        }
        __syncthreads();
        #pragma unroll
        for (int i = 0; i < 4; ++i) {
            const int unit = i*256 + tid;
            const int cg = unit & 15;
            const int hw = unit >> 4;
            uint2 o;
            o.x = pkh(t[cg*4+0][hw], t[cg*4+1][hw]);
            o.y = pkh(t[cg*4+2][hw], t[cg*4+3][hw]);
            *(uint2*)(xt + ((size_t)n*HWSZ + hw0 + hw)*CIN + cg*4) = o;
        }
    } else {
        const int gid = (bid - TP_BLOCKS)*256 + tid;
        if (gid < WSWZ_ELEMS) {
            const int j = gid & 7, o = (gid >> 3) & 63, q = (gid >> 9) & 3, s = gid >> 11;
            const int k = s*32 + q*8 + j;
            const int c = k & 63, tt = k >> 6;
            wswz[gid] = f2h(wgt[o*576 + c*9 + tt]);
        } else {
            const int g2 = gid - WSWZ_ELEMS;
            const int j = g2 & 7, r = (g2 >> 3) & 31, q = (g2 >> 8) & 3, s = g2 >> 10;
            const int k = s*32 + q*8 + j;
            const int c = k & 63, tt = k >> 6;
            oswz[g2] = (r < 27) ? f2h(offw[r*576 + c*9 + tt]) : (u16)0;
        }
    }
}

// phase-1 im2col read from LDS patch (S_ = 2*tap + h; S_&1 selects channel half)
#define IML(DST, S_) { \
    const int t_ = (S_) >> 1; \
    const int ty_ = t_/3, tx_ = t_ - 3*ty_; \
    const int r_ = row + 1 + ty_; \
    const int c_ = m + 1 + tx_; \
    const int pos_ = r_*PC + c_; \
    const int ck_ = ((S_) & 1)*4 + q; \
    DST = *(const uint4*)(patch + pos_*128 + ((ck_ ^ (pos_ & 7)) << 4)); }

#define OFF_MFMA(SRC, S_) { CV cb_; cb_.u = (SRC); \
    const u16* ap_ = oswz + ((S_)*4 + q)*256 + m*8; \
    acc0 = __builtin_amdgcn_mfma_f32_16x16x32_f16(*(const h8*)(ap_),       cb_.h, acc0, 0, 0, 0); \
    acc1 = __builtin_amdgcn_mfma_f32_16x16x32_f16(*(const h8*)(ap_ + 128), cb_.h, acc1, 0, 0, 0); }

// packed-fp16 bilinear lerp feeding MFMA B-fragment directly (one channel half)
#define HALF_STEP(R00, R01, R10, R11, TW, S_) { \
    CV cb_; \
    cb_.u.x = U2(__hfma2(H2((R00).x),(TW).w00, __hfma2(H2((R01).x),(TW).w01, \
              __hfma2(H2((R10).x),(TW).w10, __hmul2(H2((R11).x),(TW).w11))))); \
    cb_.u.y = U2(__hfma2(H2((R00).y),(TW).w00, __hfma2(H2((R01).y),(TW).w01, \
              __hfma2(H2((R10).y),(TW).w10, __hmul2(H2((R11).y),(TW).w11))))); \
    cb_.u.z = U2(__hfma2(H2((R00).z),(TW).w00, __hfma2(H2((R01).z),(TW).w01, \
              __hfma2(H2((R10).z),(TW).w10, __hmul2(H2((R11).z),(TW).w11))))); \
    cb_.u.w = U2(__hfma2(H2((R00).w),(TW).w00, __hfma2(H2((R01).w),(TW).w01, \
              __hfma2(H2((R10).w),(TW).w10, __hmul2(H2((R11).w),(TW).w11))))); \
    const u16* wp_ = wswz + ((S_)*4 + q)*512 + m*8; \
    acc[0] = __builtin_amdgcn_mfma_f32_16x16x32_f16(*(const h8*)(wp_),       cb_.h, acc[0], 0, 0, 0); \
    acc[1] = __builtin_amdgcn_mfma_f32_16x16x32_f16(*(const h8*)(wp_ + 128), cb_.h, acc[1], 0, 0, 0); \
    acc[2] = __builtin_amdgcn_mfma_f32_16x16x32_f16(*(const h8*)(wp_ + 256), cb_.h, acc[2], 0, 0, 0); \
    acc[3] = __builtin_amdgcn_mfma_f32_16x16x32_f16(*(const h8*)(wp_ + 384), cb_.h, acc[3], 0, 0, 0); }

#define UNPACK_TW(TW, WX, WY) { \
    (TW).w00 = __half2half2(__ushort_as_half((u16)((WX) & 0xFFFFu))); \
    (TW).w01 = __half2half2(__ushort_as_half((u16)((WX) >> 16))); \
    (TW).w10 = __half2half2(__ushort_as_half((u16)((WY) & 0xFFFFu))); \
    (TW).w11 = __half2half2(__ushort_as_half((u16)((WY) >> 16))); }

// ---------- fused: offset conv + sampling + main conv; 8 waves, channel-split ----------
__global__ __launch_bounds__(512)
__attribute__((amdgpu_waves_per_eu(8)))
void dcn_k(
    const u16*  __restrict__ xt,
    const u16*  __restrict__ wswz,
    const u16*  __restrict__ oswz,
    const float* __restrict__ bias,
    const float* __restrict__ offb,
    float* __restrict__ out)
{
    __shared__ uint4 patch4[PATCH_CHUNKS];   // 24,192 B (swizzled fp16 patch)
    __shared__ float rawsm[4][32][16];       //  8,192 B offset-conv raws
    __shared__ unsigned prmO[4][9][16];      //  2,304 B
    __shared__ uint2    prmW[4][9][16];      //  4,608 B  (total 39,296 -> 4 blocks/CU)
    char* patch = (char*)patch4;

    const int tid  = threadIdx.x;
    const int lane = tid & 63;
    const int wid  = tid >> 6;     // 0..7
    const int row  = wid & 3;      // output row within tile
    const int h    = wid >> 2;     // channel half: 0 -> ch 0..31, 1 -> ch 32..63
    const int m    = lane & 15;
    const int q    = lane >> 4;

    const int n   = blockIdx.x & 7;           // XCD-locality swizzle
    const int idx = blockIdx.x >> 3;          // 0..195
    const int rg  = idx / 7;
    const int cc  = idx - rg*7;
    const int hoB = rg * 4;
    const int wo0 = cc * 16;
    const int ho  = hoB + row;
    const u16* xtn = xt + (size_t)n * HWSZ * CIN;

    // ---- phase 0: cooperative patch staging (512 threads, 3 iters) ----
    #pragma unroll
    for (int i = 0; i < 3; ++i) {
        const int u = i*512 + tid;
        if (u < PATCH_CHUNKS) {
            const int pos = u >> 3, ck = u & 7;
            const int pry = pos / PC;
            const int pcx = pos - pry*PC;
            const int gy = hoB - 2 + pry;
            const int gx = wo0 - 2 + pcx;
            uint4 v = {0u,0u,0u,0u};
            if (((unsigned)gy < HH) && ((unsigned)gx < WW))
                v = *(const uint4*)(xtn + (gy*WW + gx)*CIN + ck*8);
            *(uint4*)(patch + pos*128 + ((ck ^ (pos & 7)) << 4)) = v;
        }
    }
    __syncthreads();

    // ---- phase 1+2: offset conv, K split by channel half (9 steps each wave) ----
    {
        uint4 b[3];
        floatx4 acc0 = {0.f,0.f,0.f,0.f}, acc1 = {0.f,0.f,0.f,0.f};
        IML(b[0], 0 + h) IML(b[1], 2 + h) IML(b[2], 4 + h)
        #pragma unroll
        for (int t = 0; t < 9; ++t) {
            uint4 nv;
            if (t < 6) IML(nv, 2*(t+3) + h)
            OFF_MFMA(b[t%3], 2*t + h)
            if (t < 6) b[t%3] = nv;
        }
        if (h == 0) {
            #pragma unroll
            for (int r = 0; r < 4; ++r) {
                rawsm[row][q*4 + r][m]      = acc0[r];
                rawsm[row][16 + q*4 + r][m] = acc1[r];
            }
        }
        __syncthreads();
        if (h == 1) {
            #pragma unroll
            for (int r = 0; r < 4; ++r) {
                rawsm[row][q*4 + r][m]      += acc0[r];
                rawsm[row][16 + q*4 + r][m] += acc1[r];
            }
        }
        __syncthreads();
    }

    // ---- phase 3: tap params (pair splits the 9 taps: h=0 -> 0..4, h=1 -> 5..8) ----
    auto tapParam = [&](int t, int p) {
        const int ty = t / 3, tx = t - 3*ty;
        const float py = rawsm[row][2*t][p]     + offb[2*t]     + (float)(ho - 1 + ty);
        const float px = rawsm[row][2*t + 1][p] + offb[2*t + 1] + (float)(wo0 + p - 1 + tx);
        const float mk = 1.f / (1.f + expf(-(rawsm[row][18 + t][p] + offb[18 + t])));
        const float y0f = floorf(py), x0f = floorf(px);
        const float fy = py - y0f, fx = px - x0f;
        const int y0 = (int)y0f, x0 = (int)x0f;
        const float gy = 1.f - fy, gx = 1.f - fx;
        const bool vy0 = (unsigned)y0       < HH;
        const bool vy1 = (unsigned)(y0 + 1) < HH;
        const bool vx0 = (unsigned)x0       < WW;
        const bool vx1 = (unsigned)(x0 + 1) < WW;
        const float w00 = (vy0 && vx0) ? gy*gx*mk : 0.f;
        const float w01 = (vy0 && vx1) ? gy*fx*mk : 0.f;
        const float w10 = (vy1 && vx0) ? fy*gx*mk : 0.f;
        const float w11 = (vy1 && vx1) ? fy*fx*mk : 0.f;
        const int yc0 = min(max(y0, 0), HH-1),  yc1 = min(max(y0+1, 0), HH-1);
        const int xc0 = min(max(x0, 0), WW-1),  xc1 = min(max(x0+1, 0), WW-1);
        const unsigned o00 = (unsigned)((yc0*WW + xc0)*CIN);   // < 2^20
        const unsigned dxb = (unsigned)(xc1 - xc0);   // 0/1
        const unsigned dyb = (unsigned)(yc1 - yc0);   // 0/1
        const int r0  = yc0 - (hoB - 2);
        const int c0l = xc0 - (wo0 - 2);
        const bool inp = (r0 >= 0) && (r0 + (int)dyb <= PR-1)
                      && (c0l >= 0) && (c0l + (int)dxb <= PC-1);
        const int pos00 = r0*PC + c0l;                 // <= 188, fits 8 bits
        prmO[row][t][p] = o00 | (dxb << 20) | (dyb << 21)
                        | (((unsigned)pos00 & 0xFFu) << 22)
                        | (inp ? (1u << 30) : 0u);
        uint2 Wv;
        Wv.x = (unsigned)__half_as_ushort(__float2half(w00))
             | ((unsigned)__half_as_ushort(__float2half(w01)) << 16);
        Wv.y = (unsigned)__half_as_ushort(__float2half(w10))
             | ((unsigned)__half_as_ushort(__float2half(w11)) << 16);
        prmW[row][t][p] = Wv;
    };
    if (h == 0) {
        tapParam(lane >> 4, lane & 15);                 // taps 0..3
        if (lane < 16) tapParam(4, lane & 15);          // tap 4
    } else {
        tapParam(5 + (lane >> 4), lane & 15);           // taps 5..8
    }
    __syncthreads();

    // ---- phase 4: LDS gather (own channel half) + fp16 lerp + 4 MFMA per tap ----
    floatx4 acc[4];
    #pragma unroll
    for (int i = 0; i < 4; ++i) acc[i] = (floatx4){0.f,0.f,0.f,0.f};

    const int hx = h << 6;   // byte XOR selecting channel half within a 128B chunk row

    unsigned band = 0xFFFFFFFFu;
    #pragma unroll
    for (int t = 0; t < 9; ++t) band &= prmO[row][t][m];

    if (__all((int)((band >> 30) & 1u))) {
        // ---- fast path: branchless ----
        #pragma unroll
        for (int t = 0; t < 9; ++t) {
            const unsigned Po = prmO[row][t][m];
            const uint2    Pw = prmW[row][t][m];
            const int p00 = (int)((Po >> 22) & 0xFFu);
            const int dxb = (int)((Po >> 20) & 1u);
            const int dyb = (int)((Po >> 21) & 1u);
            const int p01 = p00 + dxb;
            const int p10 = p00 + dyb*PC;
            const int p11 = p10 + dxb;
            const int a00 = (p00*128 + ((q ^ (p00 & 7)) << 4)) ^ hx;
            const int a01 = (p01*128 + ((q ^ (p01 & 7)) << 4)) ^ hx;
            const int a10 = (p10*128 + ((q ^ (p10 & 7)) << 4)) ^ hx;
            const int a11 = (p11*128 + ((q ^ (p11 & 7)) << 4)) ^ hx;
            const uint4 g0 = *(const uint4*)(patch + a00);
            const uint4 g1 = *(const uint4*)(patch + a01);
            const uint4 g2 = *(const uint4*)(patch + a10);
            const uint4 g3 = *(const uint4*)(patch + a11);
            TapW tw; UNPACK_TW(tw, Pw.x, Pw.y)
            HALF_STEP(g0, g1, g2, g3, tw, 2*t + h)
        }
    } else {
        // ---- slow path: per-tap branch with global fallback (rare) ----
        const int ch = h*32 + q*8;
        #pragma unroll
        for (int t = 0; t < 9; ++t) {
            const unsigned Po = prmO[row][t][m];
            const uint2    Pw = prmW[row][t][m];
            TapW tw; UNPACK_TW(tw, Pw.x, Pw.y)
            uint4 g0,g1,g2,g3;
            if (__all((int)((Po >> 30) & 1u))) {
                const int p00 = (int)((Po >> 22) & 0xFFu);
                const int dxb = (int)((Po >> 20) & 1u);
                const int dyb = (int)((Po >> 21) & 1u);
                const int p01 = p00 + dxb;
                const int p10 = p00 + dyb*PC;
                const int p11 = p10 + dxb;
                g0 = *(const uint4*)(patch + ((p00*128 + ((q ^ (p00 & 7)) << 4)) ^ hx));
                g1 = *(const uint4*)(patch + ((p01*128 + ((q ^ (p01 & 7)) << 4)) ^ hx));
                g2 = *(const uint4*)(patch + ((p10*128 + ((q ^ (p10 & 7)) << 4)) ^ hx));
                g3 = *(const uint4*)(patch + ((p11*128 + ((q ^ (p11 & 7)) << 4)) ^ hx));
            } else {
                const int o00 = (int)(Po & 0xFFFFFu);
                const int dx  = (int)((Po >> 20) & 1u) << 6;         // 0 or CIN
                const int dy  = (int)((Po >> 21) & 1u) * (WW*CIN);
                g0 = *(const uint4*)(xtn + o00 + ch);
                g1 = *(const uint4*)(xtn + o00 + dx + ch);
                g2 = *(const uint4*)(xtn + o00 + dy + ch);
                g3 = *(const uint4*)(xtn + o00 + dx + dy + ch);
            }
            HALF_STEP(g0, g1, g2, g3, tw, 2*t + h)
        }
    }

    // ---- epilogue: exchange partial acc through dead patch region, split stores ----
    __syncthreads();                        // everyone done reading patch
    uint4* accq = (uint4*)patch4;           // 16,384 B used of 24,192
    {
        const int wbase = ((row*2 + h)*2)*64 + lane;
        if (h == 0) {
            accq[wbase]      = *(uint4*)&acc[2];
            accq[wbase + 64] = *(uint4*)&acc[3];
        } else {
            accq[wbase]      = *(uint4*)&acc[0];
            accq[wbase + 64] = *(uint4*)&acc[1];
        }
    }
    __syncthreads();
    {
        const int pb = ((row*2 + (h ^ 1))*2)*64 + lane;
        const floatx4 o0 = *(const floatx4*)&accq[pb];
        const floatx4 o1 = *(const floatx4*)&accq[pb + 64];
        if (h == 0) { acc[0] += o0; acc[1] += o1; }
        else        { acc[2] += o0; acc[3] += o1; }
    }
    #pragma unroll
    for (int j = 0; j < 2; ++j) {
        const int ob = h*2 + j;
        #pragma unroll
        for (int r = 0; r < 4; ++r) {
            const int o = ob*16 + q*4 + r;
            out[(((size_t)n*OC + o)*HH + ho)*WW + wo0 + m] = acc[ob][r] + bias[o];
        }
    }
}

extern "C" void kernel_launch(void* const* d_in, const int* in_sizes, int n_in,
                              void* d_out, int out_size, void* d_ws, size_t ws_size,
                              hipStream_t stream)
{
    const float* x    = (const float*)d_in[0];
    const float* wgt  = (const float*)d_in[1];
    const float* bias = (const float*)d_in[2];
    const float* offw = (const float*)d_in[3];
    const float* offb = (const float*)d_in[4];
    float* out = (float*)d_out;

    u16* xt   = (u16*)d_ws;
    u16* wswz = xt + XT_ELEMS;
    u16* oswz = wswz + WSWZ_ELEMS;

    prep_k<<<dim3(TP_BLOCKS + (WSWZ_ELEMS + OSWZ_ELEMS)/256), 256, 0, stream>>>(
        x, wgt, offw, xt, wswz, oswz);
    dcn_k<<<dim3(NPOS/64), 512, 0, stream>>>(xt, wswz, oswz, bias, offb, out);
}

// Round 9
// 143.281 us; speedup vs baseline: 1.0082x; 1.0082x over previous
//
#include <hip/hip_runtime.h>
#include <hip/hip_fp16.h>
#include <math.h>

#define NB  8
#define CIN 64
#define HH  112
#define WW  112
#define OC  64
#define HWSZ (HH*WW)
#define NPOS (NB*HWSZ)

// patch geometry: 4 output rows per block, 16 cols
// rows hoB-2 .. hoB+6, cols wo0-2 .. wo0+18 (full coverage for |off|<1)
#define PR 9
#define PC 21
#define NPOSP (PR*PC)          // 189 positions
#define PATCH_CHUNKS (NPOSP*8) // 1512 x 16B = 24,192 B

#define TP_BLOCKS (HWSZ/64*NB) // 1568 transpose blocks

typedef unsigned short u16;
typedef __attribute__((ext_vector_type(8))) _Float16 h8;
typedef __attribute__((ext_vector_type(4))) float floatx4;

#define XT_ELEMS   (NB*HWSZ*CIN)   // 6,422,528 u16 (12.25 MB fp16)
#define WSWZ_ELEMS (18*4*64*8)     // 36,864 u16
#define OSWZ_ELEMS (18*4*32*8)     // 18,432 u16

union CV { uint4 u; h8 h; };

__device__ __forceinline__ u16 f2h(float f) { return __half_as_ushort(__float2half(f)); }
__device__ __forceinline__ __half2 H2(unsigned v) { union { unsigned u; __half2 h; } c; c.u = v; return c.h; }
__device__ __forceinline__ unsigned U2(__half2 h) { union { unsigned u; __half2 h; } c; c.h = h; return c.u; }
__device__ __forceinline__ unsigned pkh(float lo, float hi) {
    union { __half2 h; unsigned u; } c;
    c.h = __floats2half2_rn(lo, hi);
    return c.u;
}

struct TapW { __half2 w00, w01, w10, w11; };

// ---------- prep: transpose (NCHW f32 -> NHWC fp16) + weight swizzle ----------
__global__ __launch_bounds__(256) void prep_k(
    const float* __restrict__ x, const float* __restrict__ wgt,
    const float* __restrict__ offw,
    u16* __restrict__ xt, u16* __restrict__ wswz, u16* __restrict__ oswz)
{
    __shared__ float t[64][65];
    const int tid = threadIdx.x;
    const int bid = blockIdx.x;
    if (bid < TP_BLOCKS) {
        const int n   = bid & 7;          // XCD k handles image k
        const int hw0 = (bid >> 3) * 64;
        const int wv  = tid & 63;
        const int g   = tid >> 6;
        #pragma unroll
        for (int i = 0; i < 16; ++i) {
            const int c = i*4 + g;
            t[c][wv] = x[((size_t)n*CIN + c)*HWSZ + hw0 + wv];
        }
        __syncthreads();
        #pragma unroll
        for (int i = 0; i < 4; ++i) {
            const int unit = i*256 + tid;
            const int cg = unit & 15;
            const int hw = unit >> 4;
            uint2 o;
            o.x = pkh(t[cg*4+0][hw], t[cg*4+1][hw]);
            o.y = pkh(t[cg*4+2][hw], t[cg*4+3][hw]);
            *(uint2*)(xt + ((size_t)n*HWSZ + hw0 + hw)*CIN + cg*4) = o;
        }
    } else {
        const int gid = (bid - TP_BLOCKS)*256 + tid;
        if (gid < WSWZ_ELEMS) {
            const int j = gid & 7, o = (gid >> 3) & 63, q = (gid >> 9) & 3, s = gid >> 11;
            const int k = s*32 + q*8 + j;
            const int c = k & 63, tt = k >> 6;
            wswz[gid] = f2h(wgt[o*576 + c*9 + tt]);
        } else {
            const int g2 = gid - WSWZ_ELEMS;
            const int j = g2 & 7, r = (g2 >> 3) & 31, q = (g2 >> 8) & 3, s = g2 >> 10;
            const int k = s*32 + q*8 + j;
            const int c = k & 63, tt = k >> 6;
            oswz[g2] = (r < 27) ? f2h(offw[r*576 + c*9 + tt]) : (u16)0;
        }
    }
}

// phase-1 im2col read from LDS patch (S_ = 2*tap + h; S_&1 selects channel half)
#define IML(DST, S_) { \
    const int t_ = (S_) >> 1; \
    const int ty_ = t_/3, tx_ = t_ - 3*ty_; \
    const int r_ = row + 1 + ty_; \
    const int c_ = m + 1 + tx_; \
    const int pos_ = r_*PC + c_; \
    const int ck_ = ((S_) & 1)*4 + q; \
    DST = *(const uint4*)(patch + pos_*128 + ((ck_ ^ (pos_ & 7)) << 4)); }

#define OFF_MFMA(SRC, S_) { CV cb_; cb_.u = (SRC); \
    const u16* ap_ = oswz + ((S_)*4 + q)*256 + m*8; \
    acc0 = __builtin_amdgcn_mfma_f32_16x16x32_f16(*(const h8*)(ap_),       cb_.h, acc0, 0, 0, 0); \
    acc1 = __builtin_amdgcn_mfma_f32_16x16x32_f16(*(const h8*)(ap_ + 128), cb_.h, acc1, 0, 0, 0); }

// packed-fp16 bilinear lerp feeding MFMA B-fragment directly (one channel half)
#define HALF_STEP(R00, R01, R10, R11, TW, S_) { \
    CV cb_; \
    cb_.u.x = U2(__hfma2(H2((R00).x),(TW).w00, __hfma2(H2((R01).x),(TW).w01, \
              __hfma2(H2((R10).x),(TW).w10, __hmul2(H2((R11).x),(TW).w11))))); \
    cb_.u.y = U2(__hfma2(H2((R00).y),(TW).w00, __hfma2(H2((R01).y),(TW).w01, \
              __hfma2(H2((R10).y),(TW).w10, __hmul2(H2((R11).y),(TW).w11))))); \
    cb_.u.z = U2(__hfma2(H2((R00).z),(TW).w00, __hfma2(H2((R01).z),(TW).w01, \
              __hfma2(H2((R10).z),(TW).w10, __hmul2(H2((R11).z),(TW).w11))))); \
    cb_.u.w = U2(__hfma2(H2((R00).w),(TW).w00, __hfma2(H2((R01).w),(TW).w01, \
              __hfma2(H2((R10).w),(TW).w10, __hmul2(H2((R11).w),(TW).w11))))); \
    const u16* wp_ = wswz + ((S_)*4 + q)*512 + m*8; \
    acc[0] = __builtin_amdgcn_mfma_f32_16x16x32_f16(*(const h8*)(wp_),       cb_.h, acc[0], 0, 0, 0); \
    acc[1] = __builtin_amdgcn_mfma_f32_16x16x32_f16(*(const h8*)(wp_ + 128), cb_.h, acc[1], 0, 0, 0); \
    acc[2] = __builtin_amdgcn_mfma_f32_16x16x32_f16(*(const h8*)(wp_ + 256), cb_.h, acc[2], 0, 0, 0); \
    acc[3] = __builtin_amdgcn_mfma_f32_16x16x32_f16(*(const h8*)(wp_ + 384), cb_.h, acc[3], 0, 0, 0); }

#define UNPACK_TW(TW, WX, WY) { \
    (TW).w00 = __half2half2(__ushort_as_half((u16)((WX) & 0xFFFFu))); \
    (TW).w01 = __half2half2(__ushort_as_half((u16)((WX) >> 16))); \
    (TW).w10 = __half2half2(__ushort_as_half((u16)((WY) & 0xFFFFu))); \
    (TW).w11 = __half2half2(__ushort_as_half((u16)((WY) >> 16))); }

// ---------- fused: offset conv + sampling + main conv; 8 waves, channel-split ----------
__global__ __launch_bounds__(512)
__attribute__((amdgpu_waves_per_eu(4, 8)))
void dcn_k(
    const u16*  __restrict__ xt,
    const u16*  __restrict__ wswz,
    const u16*  __restrict__ oswz,
    const float* __restrict__ bias,
    const float* __restrict__ offb,
    float* __restrict__ out)
{
    __shared__ uint4 patch4[PATCH_CHUNKS];   // 24,192 B (swizzled fp16 patch)
    __shared__ float rawsm[4][32][16];       //  8,192 B offset-conv raws
    __shared__ unsigned prmO[4][9][16];      //  2,304 B
    __shared__ uint2    prmW[4][9][16];      //  4,608 B  (total 39,296 -> 4 blocks/CU LDS-wise)
    char* patch = (char*)patch4;

    const int tid  = threadIdx.x;
    const int lane = tid & 63;
    const int wid  = tid >> 6;     // 0..7
    const int row  = wid & 3;      // output row within tile
    const int h    = wid >> 2;     // channel half: 0 -> ch 0..31, 1 -> ch 32..63
    const int m    = lane & 15;
    const int q    = lane >> 4;

    const int n   = blockIdx.x & 7;           // XCD-locality swizzle
    const int idx = blockIdx.x >> 3;          // 0..195
    const int rg  = idx / 7;
    const int cc  = idx - rg*7;
    const int hoB = rg * 4;
    const int wo0 = cc * 16;
    const int ho  = hoB + row;
    const u16* xtn = xt + (size_t)n * HWSZ * CIN;

    // ---- phase 0: cooperative patch staging (512 threads, 3 iters) ----
    #pragma unroll
    for (int i = 0; i < 3; ++i) {
        const int u = i*512 + tid;
        if (u < PATCH_CHUNKS) {
            const int pos = u >> 3, ck = u & 7;
            const int pry = pos / PC;
            const int pcx = pos - pry*PC;
            const int gy = hoB - 2 + pry;
            const int gx = wo0 - 2 + pcx;
            uint4 v = {0u,0u,0u,0u};
            if (((unsigned)gy < HH) && ((unsigned)gx < WW))
                v = *(const uint4*)(xtn + (gy*WW + gx)*CIN + ck*8);
            *(uint4*)(patch + pos*128 + ((ck ^ (pos & 7)) << 4)) = v;
        }
    }
    __syncthreads();

    // ---- phase 1+2: offset conv, K split by channel half (9 steps each wave) ----
    {
        uint4 b[3];
        floatx4 acc0 = {0.f,0.f,0.f,0.f}, acc1 = {0.f,0.f,0.f,0.f};
        IML(b[0], 0 + h) IML(b[1], 2 + h) IML(b[2], 4 + h)
        #pragma unroll
        for (int t = 0; t < 9; ++t) {
            uint4 nv;
            if (t < 6) IML(nv, 2*(t+3) + h)
            OFF_MFMA(b[t%3], 2*t + h)
            if (t < 6) b[t%3] = nv;
        }
        if (h == 0) {
            #pragma unroll
            for (int r = 0; r < 4; ++r) {
                rawsm[row][q*4 + r][m]      = acc0[r];
                rawsm[row][16 + q*4 + r][m] = acc1[r];
            }
        }
        __syncthreads();
        if (h == 1) {
            #pragma unroll
            for (int r = 0; r < 4; ++r) {
                rawsm[row][q*4 + r][m]      += acc0[r];
                rawsm[row][16 + q*4 + r][m] += acc1[r];
            }
        }
        __syncthreads();
    }

    // ---- phase 3: tap params (pair splits the 9 taps: h=0 -> 0..4, h=1 -> 5..8) ----
    auto tapParam = [&](int t, int p) {
        const int ty = t / 3, tx = t - 3*ty;
        const float py = rawsm[row][2*t][p]     + offb[2*t]     + (float)(ho - 1 + ty);
        const float px = rawsm[row][2*t + 1][p] + offb[2*t + 1] + (float)(wo0 + p - 1 + tx);
        const float mk = 1.f / (1.f + expf(-(rawsm[row][18 + t][p] + offb[18 + t])));
        const float y0f = floorf(py), x0f = floorf(px);
        const float fy = py - y0f, fx = px - x0f;
        const int y0 = (int)y0f, x0 = (int)x0f;
        const float gy = 1.f - fy, gx = 1.f - fx;
        const bool vy0 = (unsigned)y0       < HH;
        const bool vy1 = (unsigned)(y0 + 1) < HH;
        const bool vx0 = (unsigned)x0       < WW;
        const bool vx1 = (unsigned)(x0 + 1) < WW;
        const float w00 = (vy0 && vx0) ? gy*gx*mk : 0.f;
        const float w01 = (vy0 && vx1) ? gy*fx*mk : 0.f;
        const float w10 = (vy1 && vx0) ? fy*gx*mk : 0.f;
        const float w11 = (vy1 && vx1) ? fy*fx*mk : 0.f;
        const int yc0 = min(max(y0, 0), HH-1),  yc1 = min(max(y0+1, 0), HH-1);
        const int xc0 = min(max(x0, 0), WW-1),  xc1 = min(max(x0+1, 0), WW-1);
        const unsigned o00 = (unsigned)((yc0*WW + xc0)*CIN);   // < 2^20
        const unsigned dxb = (unsigned)(xc1 - xc0);   // 0/1
        const unsigned dyb = (unsigned)(yc1 - yc0);   // 0/1
        const int r0  = yc0 - (hoB - 2);
        const int c0l = xc0 - (wo0 - 2);
        const bool inp = (r0 >= 0) && (r0 + (int)dyb <= PR-1)
                      && (c0l >= 0) && (c0l + (int)dxb <= PC-1);
        const int pos00 = r0*PC + c0l;                 // <= 188, fits 8 bits
        prmO[row][t][p] = o00 | (dxb << 20) | (dyb << 21)
                        | (((unsigned)pos00 & 0xFFu) << 22)
                        | (inp ? (1u << 30) : 0u);
        uint2 Wv;
        Wv.x = (unsigned)__half_as_ushort(__float2half(w00))
             | ((unsigned)__half_as_ushort(__float2half(w01)) << 16);
        Wv.y = (unsigned)__half_as_ushort(__float2half(w10))
             | ((unsigned)__half_as_ushort(__float2half(w11)) << 16);
        prmW[row][t][p] = Wv;
    };
    if (h == 0) {
        tapParam(lane >> 4, lane & 15);                 // taps 0..3
        if (lane < 16) tapParam(4, lane & 15);          // tap 4
    } else {
        tapParam(5 + (lane >> 4), lane & 15);           // taps 5..8
    }
    __syncthreads();

    // ---- phase 4: LDS gather (own channel half) + fp16 lerp + 4 MFMA per tap ----
    floatx4 acc[4];
    #pragma unroll
    for (int i = 0; i < 4; ++i) acc[i] = (floatx4){0.f,0.f,0.f,0.f};

    const int hx = h << 6;   // byte XOR selecting channel half within a 128B chunk row

    unsigned band = 0xFFFFFFFFu;
    #pragma unroll
    for (int t = 0; t < 9; ++t) band &= prmO[row][t][m];

    if (__all((int)((band >> 30) & 1u))) {
        // ---- fast path: branchless ----
        #pragma unroll
        for (int t = 0; t < 9; ++t) {
            const unsigned Po = prmO[row][t][m];
            const uint2    Pw = prmW[row][t][m];
            const int p00 = (int)((Po >> 22) & 0xFFu);
            const int dxb = (int)((Po >> 20) & 1u);
            const int dyb = (int)((Po >> 21) & 1u);
            const int p01 = p00 + dxb;
            const int p10 = p00 + dyb*PC;
            const int p11 = p10 + dxb;
            const int a00 = (p00*128 + ((q ^ (p00 & 7)) << 4)) ^ hx;
            const int a01 = (p01*128 + ((q ^ (p01 & 7)) << 4)) ^ hx;
            const int a10 = (p10*128 + ((q ^ (p10 & 7)) << 4)) ^ hx;
            const int a11 = (p11*128 + ((q ^ (p11 & 7)) << 4)) ^ hx;
            const uint4 g0 = *(const uint4*)(patch + a00);
            const uint4 g1 = *(const uint4*)(patch + a01);
            const uint4 g2 = *(const uint4*)(patch + a10);
            const uint4 g3 = *(const uint4*)(patch + a11);
            TapW tw; UNPACK_TW(tw, Pw.x, Pw.y)
            HALF_STEP(g0, g1, g2, g3, tw, 2*t + h)
        }
    } else {
        // ---- slow path: per-tap branch with global fallback (rare) ----
        const int ch = h*32 + q*8;
        #pragma unroll
        for (int t = 0; t < 9; ++t) {
            const unsigned Po = prmO[row][t][m];
            const uint2    Pw = prmW[row][t][m];
            TapW tw; UNPACK_TW(tw, Pw.x, Pw.y)
            uint4 g0,g1,g2,g3;
            if (__all((int)((Po >> 30) & 1u))) {
                const int p00 = (int)((Po >> 22) & 0xFFu);
                const int dxb = (int)((Po >> 20) & 1u);
                const int dyb = (int)((Po >> 21) & 1u);
                const int p01 = p00 + dxb;
                const int p10 = p00 + dyb*PC;
                const int p11 = p10 + dxb;
                g0 = *(const uint4*)(patch + ((p00*128 + ((q ^ (p00 & 7)) << 4)) ^ hx));
                g1 = *(const uint4*)(patch + ((p01*128 + ((q ^ (p01 & 7)) << 4)) ^ hx));
                g2 = *(const uint4*)(patch + ((p10*128 + ((q ^ (p10 & 7)) << 4)) ^ hx));
                g3 = *(const uint4*)(patch + ((p11*128 + ((q ^ (p11 & 7)) << 4)) ^ hx));
            } else {
                const int o00 = (int)(Po & 0xFFFFFu);
                const int dx  = (int)((Po >> 20) & 1u) << 6;         // 0 or CIN
                const int dy  = (int)((Po >> 21) & 1u) * (WW*CIN);
                g0 = *(const uint4*)(xtn + o00 + ch);
                g1 = *(const uint4*)(xtn + o00 + dx + ch);
                g2 = *(const uint4*)(xtn + o00 + dy + ch);
                g3 = *(const uint4*)(xtn + o00 + dx + dy + ch);
            }
            HALF_STEP(g0, g1, g2, g3, tw, 2*t + h)
        }
    }

    // ---- epilogue: exchange partial acc through dead patch region, split stores ----
    __syncthreads();                        // everyone done reading patch
    uint4* accq = (uint4*)patch4;           // 16,384 B used of 24,192
    {
        const int wbase = ((row*2 + h)*2)*64 + lane;
        if (h == 0) {
            accq[wbase]      = *(uint4*)&acc[2];
            accq[wbase + 64] = *(uint4*)&acc[3];
        } else {
            accq[wbase]      = *(uint4*)&acc[0];
            accq[wbase + 64] = *(uint4*)&acc[1];
        }
    }
    __syncthreads();
    {
        const int pb = ((row*2 + (h ^ 1))*2)*64 + lane;
        const floatx4 o0 = *(const floatx4*)&accq[pb];
        const floatx4 o1 = *(const floatx4*)&accq[pb + 64];
        if (h == 0) { acc[0] += o0; acc[1] += o1; }
        else        { acc[2] += o0; acc[3] += o1; }
    }
    #pragma unroll
    for (int j = 0; j < 2; ++j) {
        const int ob = h*2 + j;
        #pragma unroll
        for (int r = 0; r < 4; ++r) {
            const int o = ob*16 + q*4 + r;
            out[(((size_t)n*OC + o)*HH + ho)*WW + wo0 + m] = acc[ob][r] + bias[o];
        }
    }
}

extern "C" void kernel_launch(void* const* d_in, const int* in_sizes, int n_in,
                              void* d_out, int out_size, void* d_ws, size_t ws_size,
                              hipStream_t stream)
{
    const float* x    = (const float*)d_in[0];
    const float* wgt  = (const float*)d_in[1];
    const float* bias = (const float*)d_in[2];
    const float* offw = (const float*)d_in[3];
    const float* offb = (const float*)d_in[4];
    float* out = (float*)d_out;

    u16* xt   = (u16*)d_ws;
    u16* wswz = xt + XT_ELEMS;
    u16* oswz = wswz + WSWZ_ELEMS;

    prep_k<<<dim3(TP_BLOCKS + (WSWZ_ELEMS + OSWZ_ELEMS)/256), 256, 0, stream>>>(
        x, wgt, offw, xt, wswz, oswz);
    dcn_k<<<dim3(NPOS/64), 512, 0, stream>>>(xt, wswz, oswz, bias, offb, out);
}

// Round 11
// 114.399 us; speedup vs baseline: 1.2627x; 1.2525x over previous
//
#include <hip/hip_runtime.h>
#include <hip/hip_fp16.h>
#include <math.h>

#define NB  8
#define CIN 64
#define HH  112
#define WW  112
#define OC  64
#define HWSZ (HH*WW)
#define NPOS (NB*HWSZ)

// patch geometry: 4 output rows per block (1 per wave), 16 cols per block
// rows hoB-2 .. hoB+6 (y0 min = hoB-2, y1 max = hoB+6 -- FULL coverage for |off|<1)
// cols wo0-2 .. wo0+18
#define PR 9
#define PC 21
#define NPOSP (PR*PC)          // 189 positions
#define PATCH_CHUNKS (NPOSP*8) // 1512 x 16B = 24,192 B

#define TP_BLOCKS (HWSZ/64*NB) // 1568 transpose blocks

typedef unsigned short u16;
typedef __attribute__((ext_vector_type(8))) _Float16 h8;
typedef __attribute__((ext_vector_type(4))) float floatx4;

#define XT_ELEMS   (NB*HWSZ*CIN)   // 6,422,528 u16 (12.25 MB fp16)
#define WSWZ_ELEMS (18*4*64*8)     // 36,864 u16
#define OSWZ_ELEMS (18*4*32*8)     // 18,432 u16

union CV { uint4 u; h8 h; };

__device__ __forceinline__ u16 f2h(float f) { return __half_as_ushort(__float2half(f)); }
__device__ __forceinline__ __half2 H2(unsigned v) { union { unsigned u; __half2 h; } c; c.u = v; return c.h; }
__device__ __forceinline__ unsigned U2(__half2 h) { union { unsigned u; __half2 h; } c; c.h = h; return c.u; }
__device__ __forceinline__ unsigned pkh(float lo, float hi) {
    union { __half2 h; unsigned u; } c;
    c.h = __floats2half2_rn(lo, hi);
    return c.u;
}

struct TapW { __half2 w00, w01, w10, w11; };

// ---------- prep: transpose (NCHW f32 -> NHWC fp16) + weight swizzle ----------
__global__ __launch_bounds__(256) void prep_k(
    const float* __restrict__ x, const float* __restrict__ wgt,
    const float* __restrict__ offw,
    u16* __restrict__ xt, u16* __restrict__ wswz, u16* __restrict__ oswz)
{
    __shared__ float t[64][65];
    const int tid = threadIdx.x;
    const int bid = blockIdx.x;
    if (bid < TP_BLOCKS) {
        const int n   = bid & 7;          // XCD k handles image k
        const int hw0 = (bid >> 3) * 64;
        const int wv  = tid & 63;
        const int g   = tid >> 6;
        #pragma unroll
        for (int i = 0; i < 16; ++i) {
            const int c = i*4 + g;
            t[c][wv] = x[((size_t)n*CIN + c)*HWSZ + hw0 + wv];
        }
        __syncthreads();
        #pragma unroll
        for (int i = 0; i < 4; ++i) {
            const int unit = i*256 + tid;
            const int cg = unit & 15;
            const int hw = unit >> 4;
            uint2 o;
            o.x = pkh(t[cg*4+0][hw], t[cg*4+1][hw]);
            o.y = pkh(t[cg*4+2][hw], t[cg*4+3][hw]);
            *(uint2*)(xt + ((size_t)n*HWSZ + hw0 + hw)*CIN + cg*4) = o;
        }
    } else {
        const int gid = (bid - TP_BLOCKS)*256 + tid;
        if (gid < WSWZ_ELEMS) {
            const int j = gid & 7, o = (gid >> 3) & 63, q = (gid >> 9) & 3, s = gid >> 11;
            const int k = s*32 + q*8 + j;
            const int c = k & 63, tt = k >> 6;
            wswz[gid] = f2h(wgt[o*576 + c*9 + tt]);
        } else {
            const int g2 = gid - WSWZ_ELEMS;
            const int j = g2 & 7, r = (g2 >> 3) & 31, q = (g2 >> 8) & 3, s = g2 >> 10;
            const int k = s*32 + q*8 + j;
            const int c = k & 63, tt = k >> 6;
            oswz[g2] = (r < 27) ? f2h(offw[r*576 + c*9 + tt]) : (u16)0;
        }
    }
}

// phase-1 im2col read from LDS patch (zero-filled borders, no predicates)
#define IML(DST, S_) { \
    const int t_ = (S_) >> 1; \
    const int ty_ = t_/3, tx_ = t_ - 3*ty_; \
    const int r_ = wid + 1 + ty_; \
    const int c_ = m + 1 + tx_; \
    const int pos_ = r_*PC + c_; \
    const int ck_ = ((S_) & 1)*4 + q; \
    DST = *(const uint4*)(patch + pos_*128 + ((ck_ ^ (pos_ & 7)) << 4)); }

#define OFF_MFMA(SRC, S_) { CV cb_; cb_.u = (SRC); \
    const u16* ap_ = oswz + ((S_)*4 + q)*256 + m*8; \
    acc0 = __builtin_amdgcn_mfma_f32_16x16x32_f16(*(const h8*)(ap_),       cb_.h, acc0, 0, 0, 0); \
    acc1 = __builtin_amdgcn_mfma_f32_16x16x32_f16(*(const h8*)(ap_ + 128), cb_.h, acc1, 0, 0, 0); }

// packed-fp16 bilinear lerp feeding MFMA B-fragment directly
#define HALF_STEP(R00, R01, R10, R11, TW, S_) { \
    CV cb_; \
    cb_.u.x = U2(__hfma2(H2((R00).x),(TW).w00, __hfma2(H2((R01).x),(TW).w01, \
              __hfma2(H2((R10).x),(TW).w10, __hmul2(H2((R11).x),(TW).w11))))); \
    cb_.u.y = U2(__hfma2(H2((R00).y),(TW).w00, __hfma2(H2((R01).y),(TW).w01, \
              __hfma2(H2((R10).y),(TW).w10, __hmul2(H2((R11).y),(TW).w11))))); \
    cb_.u.z = U2(__hfma2(H2((R00).z),(TW).w00, __hfma2(H2((R01).z),(TW).w01, \
              __hfma2(H2((R10).z),(TW).w10, __hmul2(H2((R11).z),(TW).w11))))); \
    cb_.u.w = U2(__hfma2(H2((R00).w),(TW).w00, __hfma2(H2((R01).w),(TW).w01, \
              __hfma2(H2((R10).w),(TW).w10, __hmul2(H2((R11).w),(TW).w11))))); \
    const u16* wp_ = wswz + ((S_)*4 + q)*512 + m*8; \
    acc[0] = __builtin_amdgcn_mfma_f32_16x16x32_f16(*(const h8*)(wp_),       cb_.h, acc[0], 0, 0, 0); \
    acc[1] = __builtin_amdgcn_mfma_f32_16x16x32_f16(*(const h8*)(wp_ + 128), cb_.h, acc[1], 0, 0, 0); \
    acc[2] = __builtin_amdgcn_mfma_f32_16x16x32_f16(*(const h8*)(wp_ + 256), cb_.h, acc[2], 0, 0, 0); \
    acc[3] = __builtin_amdgcn_mfma_f32_16x16x32_f16(*(const h8*)(wp_ + 384), cb_.h, acc[3], 0, 0, 0); }

#define UNPACK_TW(TW, WX, WY) { \
    (TW).w00 = __half2half2(__ushort_as_half((u16)((WX) & 0xFFFFu))); \
    (TW).w01 = __half2half2(__ushort_as_half((u16)((WX) >> 16))); \
    (TW).w10 = __half2half2(__ushort_as_half((u16)((WY) & 0xFFFFu))); \
    (TW).w11 = __half2half2(__ushort_as_half((u16)((WY) >> 16))); }

// ---------- fused: offset conv + sampling + main conv (LDS-patch gather) ----------
__global__ __launch_bounds__(256)
__attribute__((amdgpu_waves_per_eu(5, 8)))
void dcn_k(
    const u16*  __restrict__ xt,
    const u16*  __restrict__ wswz,
    const u16*  __restrict__ oswz,
    const float* __restrict__ bias,
    const float* __restrict__ offb,
    float* __restrict__ out)
{
    __shared__ uint4 patch4[PATCH_CHUNKS];   // 24,192 B (swizzled fp16 patch)
    __shared__ float rawsm[4][32][16];       //  8,192 B; prm aliases this after phase 3
    char* patch = (char*)patch4;
    unsigned* prmO = (unsigned*)rawsm;                       // 2,304 B
    uint2*    prmW = (uint2*)((char*)rawsm + 2304);          // 4,608 B  (total 6,912 <= 8,192)

    const int tid  = threadIdx.x;
    const int lane = tid & 63;
    const int wid  = tid >> 6;
    const int m    = lane & 15;
    const int q    = lane >> 4;

    const int n   = blockIdx.x & 7;           // XCD-locality swizzle
    const int idx = blockIdx.x >> 3;          // 0..195
    const int rg  = idx / 7;
    const int cc  = idx - rg*7;
    const int hoB = rg * 4;
    const int wo0 = cc * 16;
    const int ho  = hoB + wid;
    const u16* xtn = xt + (size_t)n * HWSZ * CIN;

    // ---- phase 0: cooperative patch staging (coalesced, zero-filled borders) ----
    #pragma unroll
    for (int i = 0; i < 6; ++i) {
        const int u = i*256 + tid;
        if (u < PATCH_CHUNKS) {
            const int pos = u >> 3, ck = u & 7;
            const int pry = pos / PC;
            const int pcx = pos - pry*PC;
            const int gy = hoB - 2 + pry;
            const int gx = wo0 - 2 + pcx;
            uint4 v = {0u,0u,0u,0u};
            if (((unsigned)gy < HH) && ((unsigned)gx < WW))
                v = *(const uint4*)(xtn + (gy*WW + gx)*CIN + ck*8);
            *(uint4*)(patch + pos*128 + ((ck ^ (pos & 7)) << 4)) = v;
        }
    }
    __syncthreads();

    // ---- phase 1+2: offset conv from LDS patch ----
    {
        uint4 b[6];
        floatx4 acc0 = {0.f,0.f,0.f,0.f}, acc1 = {0.f,0.f,0.f,0.f};
        #pragma unroll
        for (int s = 0; s < 6; ++s) IML(b[s], s)
        #pragma unroll
        for (int s = 0; s < 6; ++s) {
            uint4 nv; IML(nv, s + 6)
            OFF_MFMA(b[s], s)
            b[s] = nv;
        }
        #pragma unroll
        for (int s = 0; s < 6; ++s) {
            uint4 nv; IML(nv, s + 12)
            OFF_MFMA(b[s], s + 6)
            b[s] = nv;
        }
        #pragma unroll
        for (int s = 0; s < 6; ++s) OFF_MFMA(b[s], s + 12)

        #pragma unroll
        for (int r = 0; r < 4; ++r) {
            rawsm[wid][q*4 + r][m]      = acc0[r];
            rawsm[wid][16 + q*4 + r][m] = acc1[r];
        }
    }
    __syncthreads();

    // ---- phase 3: tap params; prm overwrites raws (read -> barrier -> write) ----
    float vy[3], vx[3], vmk[3];
    #pragma unroll
    for (int i = 0; i < 3; ++i) {
        const int e = i*64 + lane;
        if (e < 144) {
            const int t = e >> 4, p = e & 15;
            vy[i]  = rawsm[wid][2*t][p];
            vx[i]  = rawsm[wid][2*t + 1][p];
            vmk[i] = rawsm[wid][18 + t][p];
        }
    }
    __syncthreads();
    #pragma unroll
    for (int i = 0; i < 3; ++i) {
        const int e = i*64 + lane;
        if (e < 144) {
            const int t = e >> 4;        // 0..8
            const int p = e & 15;
            const int ty = t / 3, tx = t - 3*ty;
            const float py = vy[i] + offb[2*t]     + (float)(ho - 1 + ty);
            const float px = vx[i] + offb[2*t + 1] + (float)(wo0 + p - 1 + tx);
            const float mk = 1.f / (1.f + expf(-(vmk[i] + offb[18 + t])));
            const float y0f = floorf(py), x0f = floorf(px);
            const float fy = py - y0f, fx = px - x0f;
            const int y0 = (int)y0f, x0 = (int)x0f;
            const float gy = 1.f - fy, gx = 1.f - fx;
            const bool vy0 = (unsigned)y0       < HH;
            const bool vy1 = (unsigned)(y0 + 1) < HH;
            const bool vx0 = (unsigned)x0       < WW;
            const bool vx1 = (unsigned)(x0 + 1) < WW;
            const float w00 = (vy0 && vx0) ? gy*gx*mk : 0.f;
            const float w01 = (vy0 && vx1) ? gy*fx*mk : 0.f;
            const float w10 = (vy1 && vx0) ? fy*gx*mk : 0.f;
            const float w11 = (vy1 && vx1) ? fy*fx*mk : 0.f;
            const int yc0 = min(max(y0, 0), HH-1),  yc1 = min(max(y0+1, 0), HH-1);
            const int xc0 = min(max(x0, 0), WW-1),  xc1 = min(max(x0+1, 0), WW-1);
            const unsigned o00 = (unsigned)((yc0*WW + xc0)*CIN);   // < 2^20
            const unsigned dxb = (unsigned)(xc1 - xc0);   // 0/1
            const unsigned dyb = (unsigned)(yc1 - yc0);   // 0/1
            const int r0  = yc0 - (hoB - 2);
            const int c0l = xc0 - (wo0 - 2);
            const bool inp = (r0 >= 0) && (r0 + (int)dyb <= PR-1)
                          && (c0l >= 0) && (c0l + (int)dxb <= PC-1);
            const int pos00 = r0*PC + c0l;                 // <= 188, fits 8 bits
            prmO[(wid*9 + t)*16 + p] = o00 | (dxb << 20) | (dyb << 21)
                            | (((unsigned)pos00 & 0xFFu) << 22)
                            | (inp ? (1u << 30) : 0u);
            uint2 Wv;
            Wv.x = (unsigned)__half_as_ushort(__float2half(w00))
                 | ((unsigned)__half_as_ushort(__float2half(w01)) << 16);
            Wv.y = (unsigned)__half_as_ushort(__float2half(w10))
                 | ((unsigned)__half_as_ushort(__float2half(w11)) << 16);
            prmW[(wid*9 + t)*16 + p] = Wv;
        }
    }
    __syncthreads();

    // ---- phase 4: LDS gather + packed-fp16 lerp + main MFMA ----
    floatx4 acc[4];
    #pragma unroll
    for (int i = 0; i < 4; ++i) acc[i] = (floatx4){0.f,0.f,0.f,0.f};

    const unsigned* PoB = prmO + wid*144 + m;
    const uint2*    PwB = prmW + wid*144 + m;

    // wave-uniform fast/slow split decided ONCE: AND-reduce in-patch bits of all 9 taps
    unsigned band = 0xFFFFFFFFu;
    #pragma unroll
    for (int t = 0; t < 9; ++t) band &= PoB[t*16];

    if (__all((int)((band >> 30) & 1u))) {
        // ---- fast path: branchless, Po/Pw prefetched one tap ahead ----
        unsigned Po = PoB[0];
        uint2    Pw = PwB[0];
        #pragma unroll
        for (int t = 0; t < 9; ++t) {
            const unsigned PoN = (t < 8) ? PoB[(t+1)*16] : 0u;
            const uint2    PwN = (t < 8) ? PwB[(t+1)*16] : Pw;
            const int p00 = (int)((Po >> 22) & 0xFFu);
            const int dxb = (int)((Po >> 20) & 1u);
            const int dyb = (int)((Po >> 21) & 1u);
            const int p01 = p00 + dxb;
            const int p10 = p00 + dyb*PC;
            const int p11 = p10 + dxb;
            const int a00 = p00*128 + ((q ^ (p00 & 7)) << 4);
            const int a01 = p01*128 + ((q ^ (p01 & 7)) << 4);
            const int a10 = p10*128 + ((q ^ (p10 & 7)) << 4);
            const int a11 = p11*128 + ((q ^ (p11 & 7)) << 4);
            const uint4 g0 = *(const uint4*)(patch + a00);
            const uint4 g1 = *(const uint4*)(patch + a01);
            const uint4 g2 = *(const uint4*)(patch + a10);
            const uint4 g3 = *(const uint4*)(patch + a11);
            const uint4 g4 = *(const uint4*)(patch + (a00 ^ 64));
            const uint4 g5 = *(const uint4*)(patch + (a01 ^ 64));
            const uint4 g6 = *(const uint4*)(patch + (a10 ^ 64));
            const uint4 g7 = *(const uint4*)(patch + (a11 ^ 64));
            TapW tw; UNPACK_TW(tw, Pw.x, Pw.y)
            HALF_STEP(g0, g1, g2, g3, tw, 2*t)
            HALF_STEP(g4, g5, g6, g7, tw, 2*t + 1)
            Po = PoN; Pw = PwN;
        }
    } else {
        // ---- slow path: per-tap branch with global fallback (rare) ----
        const int ch0 = q*8, ch1 = 32 + q*8;
        #pragma unroll
        for (int t = 0; t < 9; ++t) {
            const unsigned Po = PoB[t*16];
            const uint2    Pw = PwB[t*16];
            TapW tw; UNPACK_TW(tw, Pw.x, Pw.y)
            uint4 g0,g1,g2,g3,g4,g5,g6,g7;
            if (__all((int)((Po >> 30) & 1u))) {
                const int p00 = (int)((Po >> 22) & 0xFFu);
                const int dxb = (int)((Po >> 20) & 1u);
                const int dyb = (int)((Po >> 21) & 1u);
                const int p01 = p00 + dxb;
                const int p10 = p00 + dyb*PC;
                const int p11 = p10 + dxb;
                const int a00 = p00*128 + ((q ^ (p00 & 7)) << 4);
                const int a01 = p01*128 + ((q ^ (p01 & 7)) << 4);
                const int a10 = p10*128 + ((q ^ (p10 & 7)) << 4);
                const int a11 = p11*128 + ((q ^ (p11 & 7)) << 4);
                g0 = *(const uint4*)(patch + a00);
                g1 = *(const uint4*)(patch + a01);
                g2 = *(const uint4*)(patch + a10);
                g3 = *(const uint4*)(patch + a11);
                g4 = *(const uint4*)(patch + (a00 ^ 64));
                g5 = *(const uint4*)(patch + (a01 ^ 64));
                g6 = *(const uint4*)(patch + (a10 ^ 64));
                g7 = *(const uint4*)(patch + (a11 ^ 64));
            } else {
                const int o00 = (int)(Po & 0xFFFFFu);
                const int dx  = (int)((Po >> 20) & 1u) << 6;         // 0 or CIN
                const int dy  = (int)((Po >> 21) & 1u) * (WW*CIN);
                g0 = *(const uint4*)(xtn + o00 + ch0);
                g1 = *(const uint4*)(xtn + o00 + dx + ch0);
                g2 = *(const uint4*)(xtn + o00 + dy + ch0);
                g3 = *(const uint4*)(xtn + o00 + dx + dy + ch0);
                g4 = *(const uint4*)(xtn + o00 + ch1);
                g5 = *(const uint4*)(xtn + o00 + dx + ch1);
                g6 = *(const uint4*)(xtn + o00 + dy + ch1);
                g7 = *(const uint4*)(xtn + o00 + dx + dy + ch1);
            }
            HALF_STEP(g0, g1, g2, g3, tw, 2*t)
            HALF_STEP(g4, g5, g6, g7, tw, 2*t + 1)
        }
    }

    // ---- epilogue ----
    #pragma unroll
    for (int ob = 0; ob < 4; ++ob) {
        #pragma unroll
        for (int r = 0; r < 4; ++r) {
            const int o = ob*16 + q*4 + r;
            out[(((size_t)n*OC + o)*HH + ho)*WW + wo0 + m] = acc[ob][r] + bias[o];
        }
    }
}

extern "C" void kernel_launch(void* const* d_in, const int* in_sizes, int n_in,
                              void* d_out, int out_size, void* d_ws, size_t ws_size,
                              hipStream_t stream)
{
    const float* x    = (const float*)d_in[0];
    const float* wgt  = (const float*)d_in[1];
    const float* bias = (const float*)d_in[2];
    const float* offw = (const float*)d_in[3];
    const float* offb = (const float*)d_in[4];
    float* out = (float*)d_out;

    u16* xt   = (u16*)d_ws;
    u16* wswz = xt + XT_ELEMS;
    u16* oswz = wswz + WSWZ_ELEMS;

    prep_k<<<dim3(TP_BLOCKS + (WSWZ_ELEMS + OSWZ_ELEMS)/256), 256, 0, stream>>>(
        x, wgt, offw, xt, wswz, oswz);
    dcn_k<<<dim3(NPOS/64), 256, 0, stream>>>(xt, wswz, oswz, bias, offb, out);
}